// Round 25
// baseline (106.388 us; speedup 1.0000x reference)
//
#include <hip/hip_runtime.h>
#include <hip/hip_bf16.h>

// AliasFreeSampling R24: R23 champion (90.7us) with ONE change in afs_h:
// each block processes TWO adjacent grow-stripes (grid 16x256, loop with
// same LDS buffers) -> 4096 blocks (from 8192): halves build_frags
// prologues and dispatch ramp; each block's gt writes span 16 KB
// contiguous. Datapath, LDS sizes, occupancy unchanged.
//  afs_v: R23-proven (64-oh x 64-w, 25.6 KB LDS, 6 blocks/CU, per-slice
//         OOB reflect).
// gt layout: blocked [plane][stripe 32][ow 256][g%16].
// HAND-WRITTEN cvt_pk inline asm stays banned (R8/R11/R12 NaN cluster).
// Fallback (ws too small): self-contained fused kernel.

#define W_IN 512
#define H_IN 512
#define W_OUT 256
#define H_OUT 256

typedef __attribute__((ext_vector_type(8))) short short8;
typedef __attribute__((ext_vector_type(4))) float f32x4;

// ---------- compile-time filter construction ----------
constexpr double csqrt_(double x) {
  double g = x > 1.0 ? x : 1.0;
  for (int i = 0; i < 64; ++i) g = 0.5 * (g + x / g);
  return g;
}
constexpr double i0_(double x) {
  double q = x * x * 0.25, t = 1.0, s = 1.0;
  for (int m = 1; m < 40; ++m) { t *= q / ((double)m * (double)m); s += t; }
  return s;
}
struct CPad { float c[208]; };   // [64 zeros | c[0..66) | zeros]
constexpr CPad make_cp() {
  CPad R{};
  double k[65] = {};
  const double r = csqrt_(0.5);
  const double pi = 3.14159265358979323846;
  const double i0b = i0_(8.0);
  double stab[8] = {0.0, r, 1.0, r, 0.0, -r, -1.0, -r};  // sin(pi*n/4)
  double sum = 0.0;
  for (int i = 0; i < 65; ++i) {
    int n = i - 32;
    double sv;
    if (n == 0) sv = 0.25;
    else {
      int m = ((n % 8) + 8) % 8;
      sv = stab[m] / (pi * 0.25 * (double)n);
    }
    double t = (2.0 * i - 65.0) / 65.0;  // kaiser(66)[i]
    double a = 1.0 - t * t;
    double w = i0_(8.0 * csqrt_(a < 0.0 ? 0.0 : a)) / i0b;
    k[i] = sv * w;
    sum += k[i];
  }
  for (int i = 0; i < 65; ++i) k[i] /= sum;
  for (int s = 0; s < 66; ++s) {
    double a = s < 65 ? k[s] : 0.0;
    double b = s > 0 ? k[s - 1] : 0.0;
    R.c[64 + s] = (float)(0.5 * (a + b));
  }
  return R;
}
__constant__ CPad dCP = make_cp();

__device__ __forceinline__ unsigned bf16_rne(float f) {
  unsigned u = __float_as_uint(f);
  return (u + 0x7FFFu + ((u >> 16) & 1u)) >> 16;
}
// Native pair pack: low halfword = lo, high = hi (RNE, same as bf16_rne).
__device__ __forceinline__ unsigned pk_bf16(float lo, float hi) {
  __hip_bfloat162 h = __float22bfloat162_rn(make_float2(lo, hi));
  union { __hip_bfloat162 h2; unsigned u; } c;
  c.h2 = h;
  return c.u;
}
__device__ __forceinline__ int refl(int i, int n) {
  if (i < 0) i = -i;
  if (i >= n) i = 2 * n - 2 - i;
  return i;
}

__device__ __forceinline__ void build_frags(short8* cb, short8* cl,
                                            int la, int hg) {
#pragma unroll
  for (int kb = 0; kb < 3; ++kb) {
    union { unsigned short u[8]; short8 s8; } H, L;
#pragma unroll
    for (int j = 0; j < 8; ++j) {
      float v = dCP.c[64 + 32 * kb + 8 * hg + j - 2 * la];
      unsigned hi = bf16_rne(v);
      float res = v - __uint_as_float(hi << 16);
      H.u[j] = (unsigned short)hi;
      L.u[j] = (unsigned short)bf16_rne(res);
    }
    cb[kb] = H.s8;
    cl[kb] = L.s8;
  }
}

#define MFMA6(acc, A0, A1, A2, B0, B1, B2)                                   \
  acc = __builtin_amdgcn_mfma_f32_16x16x32_bf16(A0, B0, acc, 0, 0, 0);       \
  acc = __builtin_amdgcn_mfma_f32_16x16x32_bf16(A1, B1, acc, 0, 0, 0);       \
  acc = __builtin_amdgcn_mfma_f32_16x16x32_bf16(A2, B2, acc, 0, 0, 0);

// gt layout (ushort units): plane stride 131072, 16-g stripe 4096, ow 16
#define GT_P 131072
#define GT_S 4096

// ==================== Kernel A: horizontal + w-pool (2 stripes/block) =====
#define ASTR 600
#define GTSTR 24

__global__ __launch_bounds__(256, 5) void afs_h(
    const float* __restrict__ x, unsigned short* __restrict__ gtg) {
  __shared__ unsigned short raw[16 * ASTR];     // 19.2 KB
  __shared__ unsigned short gts[256 * GTSTR];   // 12.3 KB

  const int plane = blockIdx.y;
  const int tid = threadIdx.x;
  const int lane = tid & 63, wave = tid >> 6;
  const int la = lane & 15, hg = lane >> 4;

  short8 cb[3], cl[3];
  build_frags(cb, cl, la, hg);

  for (int sub = 0; sub < 2; ++sub) {
    const int stripe = 2 * blockIdx.x + sub;    // grow stripe [0,32)
    const float* xp = x + (size_t)plane * (W_IN * H_IN) +
                      (size_t)stripe * 16 * W_IN;

    // ---- stage 16 input rows as bf16, padded [-32, 544) ----
#pragma unroll
    for (int i = 0; i < 8; ++i) {
      int idx = i * 256 + tid;
      int r = idx >> 7, s = idx & 127;
      float4 v = *(const float4*)(xp + r * W_IN + 4 * s);
      uint2 pk;
      pk.x = pk_bf16(v.x, v.y);
      pk.y = pk_bf16(v.z, v.w);
      *(uint2*)&raw[r * ASTR + 32 + 4 * s] = pk;
    }
    {
      int r = tid >> 4, p = tid & 15;
      int pi = (p < 8) ? 4 * p : 544 + 4 * (p - 8);
      float e[4];
#pragma unroll
      for (int j = 0; j < 4; ++j)
        e[j] = xp[r * W_IN + refl(pi + j - 32, W_IN)];
      uint2 pk;
      pk.x = pk_bf16(e[0], e[1]);
      pk.y = pk_bf16(e[2], e[3]);
      *(uint2*)&raw[r * ASTR + pi] = pk;
    }
    __syncthreads();

    // ---- MFMA: 16 ow-blocks / 4 waves ----
#pragma unroll
    for (int i = 0; i < 4; ++i) {
      int owb = wave + 4 * i;
      const unsigned short* ar = &raw[la * ASTR + 32 * owb + 8 * hg];
      short8 a0 = *(const short8*)(ar + 0);
      short8 a1 = *(const short8*)(ar + 32);
      short8 a2 = *(const short8*)(ar + 64);
      f32x4 acc = {0.f, 0.f, 0.f, 0.f};
      MFMA6(acc, a0, a1, a2, cb[0], cb[1], cb[2]);
      MFMA6(acc, a0, a1, a2, cl[0], cl[1], cl[2]);
      uint2 pk;
      pk.x = pk_bf16(acc[0], acc[1]);
      pk.y = pk_bf16(acc[2], acc[3]);
      *(uint2*)&gts[(16 * owb + la) * GTSTR + 4 * hg] = pk;
    }
    __syncthreads();

    // ---- write slab -> gt[plane][stripe][ow][g16]: contiguous 8 KB ----
#pragma unroll
    for (int q = 0; q < 2; ++q) {
      int task = q * 256 + tid;
      int ow = task >> 1, half = task & 1;
      uint4 v = *(const uint4*)&gts[ow * GTSTR + 8 * half];
      *(uint4*)&gtg[(size_t)plane * GT_P + (size_t)stripe * GT_S +
                    ow * 16 + 8 * half] = v;
    }
    if (sub == 0) __syncthreads();   // gts reuse ordering for stripe 2
  }
}

// ==================== Kernel B: vertical + h-pool (staged, 64-oh x 64-w) ==
#define BSTR 200   // staged row stride (ushorts): 192 g + 8 pad

__global__ __launch_bounds__(256, 6) void afs_v(
    const unsigned short* __restrict__ gtg, float* __restrict__ out) {
  __shared__ unsigned short st[64 * BSTR];   // 25.6 KB: [w 64][g 192+pad]

  const int os = blockIdx.x;     // oh stripe [0,4): 64 oh each
  const int wq = blockIdx.y;     // w quarter [0,4): 64 w each
  const int plane = blockIdx.z;
  const int oh0 = 64 * os, w0 = 64 * wq;
  const int tid = threadIdx.x;
  const int lane = tid & 63, wave = tid >> 6;
  const int la = lane & 15, hg = lane >> 4;
  const unsigned short* gpp = gtg + (size_t)plane * GT_P;
  float* op = out + (size_t)plane * (W_OUT * H_OUT);

  short8 cb[3], cl[3];
  build_frags(cb, cl, la, hg);

  // ---- stage 12 slices of [64 w][16 g]; 2 slices per unrolled step
  // (tid>>7 is wave-uniform -> no divergence). Per-slice OOB reflect. ----
  const int half_ = tid >> 7;          // [0,2), wave-pair id
  const int within = tid & 127;
  const int wl = within >> 1;          // w local [0,64)
  const int ghalf = (within & 1) * 8;  // 0 or 8 within 16-g slice
#pragma unroll
  for (int i = 0; i < 6; ++i) {
    int sl = 2 * i + half_;            // local slice [0,12)
    int si = 8 * os - 2 + sl;          // global 16-g slice index
    int ldsoff = wl * BSTR + 16 * sl + ghalf;
    if (si >= 0 && si < 32) {
      uint4 v = *(const uint4*)&gpp[(size_t)si * GT_S + (w0 + wl) * 16 + ghalf];
      *(uint4*)&st[ldsoff] = v;
    } else {
      union { unsigned short u[8]; uint4 v; } T;
#pragma unroll
      for (int j = 0; j < 8; ++j) {
        int g = 16 * si + ghalf + j;
        int gr = refl(g, 512);
        T.u[j] = gpp[(size_t)(gr >> 4) * GT_S + (w0 + wl) * 16 + (gr & 15)];
      }
      *(uint4*)&st[ldsoff] = T.v;
    }
  }
  __syncthreads();

  // ---- MFMA: 16 subtiles (4 oh-blocks x 4 w-blocks) / 4 waves ----
#pragma unroll
  for (int i = 0; i < 4; ++i) {
    int id = wave + 4 * i;            // [0,16)
    int ob = id >> 2;                 // oh 16-block [0,4)
    int wb = id & 3;                  // w 16-block [0,4)
    const unsigned short* br = &st[(16 * wb + la) * BSTR + 32 * ob + 8 * hg];
    short8 b0 = *(const short8*)(br + 0);
    short8 b1 = *(const short8*)(br + 32);
    short8 b2 = *(const short8*)(br + 64);
    f32x4 acc = {0.f, 0.f, 0.f, 0.f};
    MFMA6(acc, cb[0], cb[1], cb[2], b0, b1, b2);
    MFMA6(acc, cl[0], cl[1], cl[2], b0, b1, b2);
    int ow = w0 + 16 * wb + la;
#pragma unroll
    for (int r = 0; r < 4; ++r)
      op[(size_t)(oh0 + 16 * ob + 4 * hg + r) * W_OUT + ow] = acc[r];
  }
}

// ==================== Fallback: fused (self-contained) ====================
#define LSTR 200
#define NCH 6

__global__ __launch_bounds__(512, 6) void afs_fused(
    const float* __restrict__ x, float* __restrict__ out) {
  __shared__ unsigned short raw[2][32 * LSTR];
  __shared__ unsigned short gt[64 * LSTR];

  const int plane = blockIdx.z;
  const int OH0 = blockIdx.y * 64;
  const int OW0 = blockIdx.x * 64;
  const int W0 = 2 * OW0 - 32;
  const int rb = 2 * OH0 - 32;
  const float* xp = x + (size_t)plane * (W_IN * H_IN);
  float* op = out + (size_t)plane * (W_OUT * H_OUT);
  const int tid = threadIdx.x;
  const int lane = tid & 63;
  const int wave = tid >> 6;
  const int la = lane & 15;
  const int lg = lane >> 4;

  short8 ch[3], cl[3];
  build_frags(ch, cl, la, lg);

  int sr[3], sc[3];
  bool sin_[3];
#pragma unroll
  for (int it = 0; it < 3; ++it) {
    int f = it * 512 + tid;
    sr[it] = f / 48;
    int s = f - 48 * sr[it];
    sc[it] = W0 + 4 * s;
    sin_[it] = (sc[it] >= 0) && (sc[it] + 4 <= W_IN);
  }
  const int rs = wave >> 2;
  const int ws = wave & 3;

  float4 pf[3];
#pragma unroll
  for (int it = 0; it < 3; ++it) {
    int h = refl(rb + sr[it], H_IN);
    const float* xrow = xp + (size_t)h * W_IN;
    if (sin_[it]) pf[it] = *(const float4*)(xrow + sc[it]);
    else {
      pf[it].x = xrow[refl(sc[it] + 0, W_IN)];
      pf[it].y = xrow[refl(sc[it] + 1, W_IN)];
      pf[it].z = xrow[refl(sc[it] + 2, W_IN)];
      pf[it].w = xrow[refl(sc[it] + 3, W_IN)];
    }
  }

  for (int k = 0; k < NCH; ++k) {
    unsigned short* rk = &raw[k & 1][0];
#pragma unroll
    for (int it = 0; it < 3; ++it) {
      uint2 pk;
      pk.x = bf16_rne(pf[it].x) | (bf16_rne(pf[it].y) << 16);
      pk.y = bf16_rne(pf[it].z) | (bf16_rne(pf[it].w) << 16);
      *(uint2*)&rk[sr[it] * LSTR + (sc[it] - W0)] = pk;
    }
    if (k + 1 < NCH) {
#pragma unroll
      for (int it = 0; it < 3; ++it) {
        int h = refl(rb + 32 * (k + 1) + sr[it], H_IN);
        const float* xrow = xp + (size_t)h * W_IN;
        if (sin_[it]) pf[it] = *(const float4*)(xrow + sc[it]);
        else {
          pf[it].x = xrow[refl(sc[it] + 0, W_IN)];
          pf[it].y = xrow[refl(sc[it] + 1, W_IN)];
          pf[it].z = xrow[refl(sc[it] + 2, W_IN)];
          pf[it].w = xrow[refl(sc[it] + 3, W_IN)];
        }
      }
    }
    __syncthreads();
    {
      const unsigned short* ar = &rk[(16 * rs + la) * LSTR + 32 * ws + 8 * lg];
      short8 a0 = *(const short8*)(ar + 0);
      short8 a1 = *(const short8*)(ar + 32);
      short8 a2 = *(const short8*)(ar + 64);
      f32x4 acc = {0.f, 0.f, 0.f, 0.f};
      MFMA6(acc, a0, a1, a2, ch[0], ch[1], ch[2]);
      MFMA6(acc, a0, a1, a2, cl[0], cl[1], cl[2]);
      uint2 pk;
      pk.x = bf16_rne(acc[0]) | (bf16_rne(acc[1]) << 16);
      pk.y = bf16_rne(acc[2]) | (bf16_rne(acc[3]) << 16);
      *(uint2*)&gt[(16 * ws + la) * LSTR + 32 * k + 16 * rs + 4 * lg] = pk;
    }
  }
  __syncthreads();

#pragma unroll
  for (int i = 0; i < 2; ++i) {
    int id = wave + 8 * i;
    int osb = id >> 2;
    int wsub = id & 3;
    const unsigned short* br = &gt[(16 * wsub + la) * LSTR + 32 * osb + 8 * lg];
    short8 b0 = *(const short8*)(br + 0);
    short8 b1 = *(const short8*)(br + 32);
    short8 b2 = *(const short8*)(br + 64);
    f32x4 acc = {0.f, 0.f, 0.f, 0.f};
    MFMA6(acc, ch[0], ch[1], ch[2], b0, b1, b2);
    MFMA6(acc, cl[0], cl[1], cl[2], b0, b1, b2);
    int ow = OW0 + 16 * wsub + la;
#pragma unroll
    for (int r = 0; r < 4; ++r) {
      int oh = OH0 + 16 * osb + 4 * lg + r;
      op[(size_t)oh * W_OUT + ow] = acc[r];
    }
  }
}

extern "C" void kernel_launch(void* const* d_in, const int* in_sizes, int n_in,
                              void* d_out, int out_size, void* d_ws, size_t ws_size,
                              hipStream_t stream) {
  const float* x = (const float*)d_in[0];   // (8,32,512,512) fp32
  float* out = (float*)d_out;               // (8,32,256,256) fp32

  const size_t GT_BYTES = (size_t)256 * GT_P * 2;  // 64 MiB bf16
  if (ws_size >= GT_BYTES) {
    unsigned short* gtg = (unsigned short*)d_ws;
    dim3 ga(16, 256);          // stripe-pair x plane
    afs_h<<<ga, 256, 0, stream>>>(x, gtg);
    dim3 gb(4, 4, 256);        // oh-stripe x w-quarter x plane
    afs_v<<<gb, 256, 0, stream>>>(gtg, out);
  } else {
    dim3 g(4, 4, 256);
    afs_fused<<<g, 512, 0, stream>>>(x, out);
  }
}

// Round 26
// 90.510 us; speedup vs baseline: 1.1754x; 1.1754x over previous
//
#include <hip/hip_runtime.h>
#include <hip/hip_bf16.h>

// AliasFreeSampling R25: exact revert to the R23 champion (90.7us).
// R24's 2-stripes-per-block amortization regressed +17%: in-block serial
// stripe chain (stage2 waits on write1+barrier) destroyed the inter-block
// overlap that 8192 independent blocks provide; prologue savings trivial.
// Final structure:
//  afs_h: 8192 blocks (stripe x plane), 16-row stripes: coalesced fp32
//         stage -> bf16 LDS (native pair cvt) -> 16x16x32 MFMA x6 (hi/lo
//         coef split) -> gts slab -> contiguous 8KB gt write; 5 blocks/CU.
//  afs_v: 4096 blocks (64-oh x 64-w), 12-slice staged window from blocked
//         gt (1.5x amp, L3-resident), per-slice OOB reflect, 6 blocks/CU.
// gt layout: blocked [plane][stripe 32][ow 256][g%16] -> all global
// traffic is lane-sequential uint4 (the session's recurring lesson).
// Fallback (ws too small): self-contained fused kernel.

#define W_IN 512
#define H_IN 512
#define W_OUT 256
#define H_OUT 256

typedef __attribute__((ext_vector_type(8))) short short8;
typedef __attribute__((ext_vector_type(4))) float f32x4;

// ---------- compile-time filter construction ----------
constexpr double csqrt_(double x) {
  double g = x > 1.0 ? x : 1.0;
  for (int i = 0; i < 64; ++i) g = 0.5 * (g + x / g);
  return g;
}
constexpr double i0_(double x) {
  double q = x * x * 0.25, t = 1.0, s = 1.0;
  for (int m = 1; m < 40; ++m) { t *= q / ((double)m * (double)m); s += t; }
  return s;
}
struct CPad { float c[208]; };   // [64 zeros | c[0..66) | zeros]
constexpr CPad make_cp() {
  CPad R{};
  double k[65] = {};
  const double r = csqrt_(0.5);
  const double pi = 3.14159265358979323846;
  const double i0b = i0_(8.0);
  double stab[8] = {0.0, r, 1.0, r, 0.0, -r, -1.0, -r};  // sin(pi*n/4)
  double sum = 0.0;
  for (int i = 0; i < 65; ++i) {
    int n = i - 32;
    double sv;
    if (n == 0) sv = 0.25;
    else {
      int m = ((n % 8) + 8) % 8;
      sv = stab[m] / (pi * 0.25 * (double)n);
    }
    double t = (2.0 * i - 65.0) / 65.0;  // kaiser(66)[i]
    double a = 1.0 - t * t;
    double w = i0_(8.0 * csqrt_(a < 0.0 ? 0.0 : a)) / i0b;
    k[i] = sv * w;
    sum += k[i];
  }
  for (int i = 0; i < 65; ++i) k[i] /= sum;
  for (int s = 0; s < 66; ++s) {
    double a = s < 65 ? k[s] : 0.0;
    double b = s > 0 ? k[s - 1] : 0.0;
    R.c[64 + s] = (float)(0.5 * (a + b));
  }
  return R;
}
__constant__ CPad dCP = make_cp();

__device__ __forceinline__ unsigned bf16_rne(float f) {
  unsigned u = __float_as_uint(f);
  return (u + 0x7FFFu + ((u >> 16) & 1u)) >> 16;
}
// Native pair pack: low halfword = lo, high = hi (RNE, same as bf16_rne).
__device__ __forceinline__ unsigned pk_bf16(float lo, float hi) {
  __hip_bfloat162 h = __float22bfloat162_rn(make_float2(lo, hi));
  union { __hip_bfloat162 h2; unsigned u; } c;
  c.h2 = h;
  return c.u;
}
__device__ __forceinline__ int refl(int i, int n) {
  if (i < 0) i = -i;
  if (i >= n) i = 2 * n - 2 - i;
  return i;
}

__device__ __forceinline__ void build_frags(short8* cb, short8* cl,
                                            int la, int hg) {
#pragma unroll
  for (int kb = 0; kb < 3; ++kb) {
    union { unsigned short u[8]; short8 s8; } H, L;
#pragma unroll
    for (int j = 0; j < 8; ++j) {
      float v = dCP.c[64 + 32 * kb + 8 * hg + j - 2 * la];
      unsigned hi = bf16_rne(v);
      float res = v - __uint_as_float(hi << 16);
      H.u[j] = (unsigned short)hi;
      L.u[j] = (unsigned short)bf16_rne(res);
    }
    cb[kb] = H.s8;
    cl[kb] = L.s8;
  }
}

#define MFMA6(acc, A0, A1, A2, B0, B1, B2)                                   \
  acc = __builtin_amdgcn_mfma_f32_16x16x32_bf16(A0, B0, acc, 0, 0, 0);       \
  acc = __builtin_amdgcn_mfma_f32_16x16x32_bf16(A1, B1, acc, 0, 0, 0);       \
  acc = __builtin_amdgcn_mfma_f32_16x16x32_bf16(A2, B2, acc, 0, 0, 0);

// gt layout (ushort units): plane stride 131072, 16-g stripe 4096, ow 16
#define GT_P 131072
#define GT_S 4096

// ==================== Kernel A: horizontal + w-pool ====================
#define ASTR 600
#define GTSTR 24

__global__ __launch_bounds__(256, 5) void afs_h(
    const float* __restrict__ x, unsigned short* __restrict__ gtg) {
  __shared__ unsigned short raw[16 * ASTR];     // 19.2 KB
  __shared__ unsigned short gts[256 * GTSTR];   // 12.3 KB

  const int stripe = blockIdx.x;        // grow stripe [0,32)
  const int plane = blockIdx.y;
  const int tid = threadIdx.x;
  const int lane = tid & 63, wave = tid >> 6;
  const int la = lane & 15, hg = lane >> 4;
  const float* xp = x + (size_t)plane * (W_IN * H_IN) + (size_t)stripe * 16 * W_IN;

  short8 cb[3], cl[3];
  build_frags(cb, cl, la, hg);

  // ---- stage 16 input rows as bf16, padded [-32, 544) ----
#pragma unroll
  for (int i = 0; i < 8; ++i) {
    int idx = i * 256 + tid;
    int r = idx >> 7, s = idx & 127;
    float4 v = *(const float4*)(xp + r * W_IN + 4 * s);
    uint2 pk;
    pk.x = pk_bf16(v.x, v.y);
    pk.y = pk_bf16(v.z, v.w);
    *(uint2*)&raw[r * ASTR + 32 + 4 * s] = pk;
  }
  {
    int r = tid >> 4, p = tid & 15;
    int pi = (p < 8) ? 4 * p : 544 + 4 * (p - 8);
    float e[4];
#pragma unroll
    for (int j = 0; j < 4; ++j)
      e[j] = xp[r * W_IN + refl(pi + j - 32, W_IN)];
    uint2 pk;
    pk.x = pk_bf16(e[0], e[1]);
    pk.y = pk_bf16(e[2], e[3]);
    *(uint2*)&raw[r * ASTR + pi] = pk;
  }
  __syncthreads();

  // ---- MFMA: 16 ow-blocks / 4 waves ----
#pragma unroll
  for (int i = 0; i < 4; ++i) {
    int owb = wave + 4 * i;
    const unsigned short* ar = &raw[la * ASTR + 32 * owb + 8 * hg];
    short8 a0 = *(const short8*)(ar + 0);
    short8 a1 = *(const short8*)(ar + 32);
    short8 a2 = *(const short8*)(ar + 64);
    f32x4 acc = {0.f, 0.f, 0.f, 0.f};
    MFMA6(acc, a0, a1, a2, cb[0], cb[1], cb[2]);
    MFMA6(acc, a0, a1, a2, cl[0], cl[1], cl[2]);
    uint2 pk;
    pk.x = pk_bf16(acc[0], acc[1]);
    pk.y = pk_bf16(acc[2], acc[3]);
    *(uint2*)&gts[(16 * owb + la) * GTSTR + 4 * hg] = pk;
  }
  __syncthreads();

  // ---- write slab -> gt[plane][stripe][ow][g16]: contiguous 8 KB ----
#pragma unroll
  for (int q = 0; q < 2; ++q) {
    int task = q * 256 + tid;
    int ow = task >> 1, half = task & 1;
    uint4 v = *(const uint4*)&gts[ow * GTSTR + 8 * half];
    *(uint4*)&gtg[(size_t)plane * GT_P + (size_t)stripe * GT_S +
                  ow * 16 + 8 * half] = v;
  }
}

// ==================== Kernel B: vertical + h-pool (staged, 64-oh x 64-w) ==
#define BSTR 200   // staged row stride (ushorts): 192 g + 8 pad

__global__ __launch_bounds__(256, 6) void afs_v(
    const unsigned short* __restrict__ gtg, float* __restrict__ out) {
  __shared__ unsigned short st[64 * BSTR];   // 25.6 KB: [w 64][g 192+pad]

  const int os = blockIdx.x;     // oh stripe [0,4): 64 oh each
  const int wq = blockIdx.y;     // w quarter [0,4): 64 w each
  const int plane = blockIdx.z;
  const int oh0 = 64 * os, w0 = 64 * wq;
  const int tid = threadIdx.x;
  const int lane = tid & 63, wave = tid >> 6;
  const int la = lane & 15, hg = lane >> 4;
  const unsigned short* gpp = gtg + (size_t)plane * GT_P;
  float* op = out + (size_t)plane * (W_OUT * H_OUT);

  short8 cb[3], cl[3];
  build_frags(cb, cl, la, hg);

  // ---- stage 12 slices of [64 w][16 g]; 2 slices per unrolled step
  // (tid>>7 is wave-uniform -> no divergence). Per-slice OOB reflect. ----
  const int half_ = tid >> 7;          // [0,2), wave-pair id
  const int within = tid & 127;
  const int wl = within >> 1;          // w local [0,64)
  const int ghalf = (within & 1) * 8;  // 0 or 8 within 16-g slice
#pragma unroll
  for (int i = 0; i < 6; ++i) {
    int sl = 2 * i + half_;            // local slice [0,12)
    int si = 8 * os - 2 + sl;          // global 16-g slice index
    int ldsoff = wl * BSTR + 16 * sl + ghalf;
    if (si >= 0 && si < 32) {
      uint4 v = *(const uint4*)&gpp[(size_t)si * GT_S + (w0 + wl) * 16 + ghalf];
      *(uint4*)&st[ldsoff] = v;
    } else {
      union { unsigned short u[8]; uint4 v; } T;
#pragma unroll
      for (int j = 0; j < 8; ++j) {
        int g = 16 * si + ghalf + j;
        int gr = refl(g, 512);
        T.u[j] = gpp[(size_t)(gr >> 4) * GT_S + (w0 + wl) * 16 + (gr & 15)];
      }
      *(uint4*)&st[ldsoff] = T.v;
    }
  }
  __syncthreads();

  // ---- MFMA: 16 subtiles (4 oh-blocks x 4 w-blocks) / 4 waves ----
#pragma unroll
  for (int i = 0; i < 4; ++i) {
    int id = wave + 4 * i;            // [0,16)
    int ob = id >> 2;                 // oh 16-block [0,4)
    int wb = id & 3;                  // w 16-block [0,4)
    const unsigned short* br = &st[(16 * wb + la) * BSTR + 32 * ob + 8 * hg];
    short8 b0 = *(const short8*)(br + 0);
    short8 b1 = *(const short8*)(br + 32);
    short8 b2 = *(const short8*)(br + 64);
    f32x4 acc = {0.f, 0.f, 0.f, 0.f};
    MFMA6(acc, cb[0], cb[1], cb[2], b0, b1, b2);
    MFMA6(acc, cl[0], cl[1], cl[2], b0, b1, b2);
    int ow = w0 + 16 * wb + la;
#pragma unroll
    for (int r = 0; r < 4; ++r)
      op[(size_t)(oh0 + 16 * ob + 4 * hg + r) * W_OUT + ow] = acc[r];
  }
}

// ==================== Fallback: fused (self-contained) ====================
#define LSTR 200
#define NCH 6

__global__ __launch_bounds__(512, 6) void afs_fused(
    const float* __restrict__ x, float* __restrict__ out) {
  __shared__ unsigned short raw[2][32 * LSTR];
  __shared__ unsigned short gt[64 * LSTR];

  const int plane = blockIdx.z;
  const int OH0 = blockIdx.y * 64;
  const int OW0 = blockIdx.x * 64;
  const int W0 = 2 * OW0 - 32;
  const int rb = 2 * OH0 - 32;
  const float* xp = x + (size_t)plane * (W_IN * H_IN);
  float* op = out + (size_t)plane * (W_OUT * H_OUT);
  const int tid = threadIdx.x;
  const int lane = tid & 63;
  const int wave = tid >> 6;
  const int la = lane & 15;
  const int lg = lane >> 4;

  short8 ch[3], cl[3];
  build_frags(ch, cl, la, lg);

  int sr[3], sc[3];
  bool sin_[3];
#pragma unroll
  for (int it = 0; it < 3; ++it) {
    int f = it * 512 + tid;
    sr[it] = f / 48;
    int s = f - 48 * sr[it];
    sc[it] = W0 + 4 * s;
    sin_[it] = (sc[it] >= 0) && (sc[it] + 4 <= W_IN);
  }
  const int rs = wave >> 2;
  const int ws = wave & 3;

  float4 pf[3];
#pragma unroll
  for (int it = 0; it < 3; ++it) {
    int h = refl(rb + sr[it], H_IN);
    const float* xrow = xp + (size_t)h * W_IN;
    if (sin_[it]) pf[it] = *(const float4*)(xrow + sc[it]);
    else {
      pf[it].x = xrow[refl(sc[it] + 0, W_IN)];
      pf[it].y = xrow[refl(sc[it] + 1, W_IN)];
      pf[it].z = xrow[refl(sc[it] + 2, W_IN)];
      pf[it].w = xrow[refl(sc[it] + 3, W_IN)];
    }
  }

  for (int k = 0; k < NCH; ++k) {
    unsigned short* rk = &raw[k & 1][0];
#pragma unroll
    for (int it = 0; it < 3; ++it) {
      uint2 pk;
      pk.x = bf16_rne(pf[it].x) | (bf16_rne(pf[it].y) << 16);
      pk.y = bf16_rne(pf[it].z) | (bf16_rne(pf[it].w) << 16);
      *(uint2*)&rk[sr[it] * LSTR + (sc[it] - W0)] = pk;
    }
    if (k + 1 < NCH) {
#pragma unroll
      for (int it = 0; it < 3; ++it) {
        int h = refl(rb + 32 * (k + 1) + sr[it], H_IN);
        const float* xrow = xp + (size_t)h * W_IN;
        if (sin_[it]) pf[it] = *(const float4*)(xrow + sc[it]);
        else {
          pf[it].x = xrow[refl(sc[it] + 0, W_IN)];
          pf[it].y = xrow[refl(sc[it] + 1, W_IN)];
          pf[it].z = xrow[refl(sc[it] + 2, W_IN)];
          pf[it].w = xrow[refl(sc[it] + 3, W_IN)];
        }
      }
    }
    __syncthreads();
    {
      const unsigned short* ar = &rk[(16 * rs + la) * LSTR + 32 * ws + 8 * lg];
      short8 a0 = *(const short8*)(ar + 0);
      short8 a1 = *(const short8*)(ar + 32);
      short8 a2 = *(const short8*)(ar + 64);
      f32x4 acc = {0.f, 0.f, 0.f, 0.f};
      MFMA6(acc, a0, a1, a2, ch[0], ch[1], ch[2]);
      MFMA6(acc, a0, a1, a2, cl[0], cl[1], cl[2]);
      uint2 pk;
      pk.x = bf16_rne(acc[0]) | (bf16_rne(acc[1]) << 16);
      pk.y = bf16_rne(acc[2]) | (bf16_rne(acc[3]) << 16);
      *(uint2*)&gt[(16 * ws + la) * LSTR + 32 * k + 16 * rs + 4 * lg] = pk;
    }
  }
  __syncthreads();

#pragma unroll
  for (int i = 0; i < 2; ++i) {
    int id = wave + 8 * i;
    int osb = id >> 2;
    int wsub = id & 3;
    const unsigned short* br = &gt[(16 * wsub + la) * LSTR + 32 * osb + 8 * lg];
    short8 b0 = *(const short8*)(br + 0);
    short8 b1 = *(const short8*)(br + 32);
    short8 b2 = *(const short8*)(br + 64);
    f32x4 acc = {0.f, 0.f, 0.f, 0.f};
    MFMA6(acc, ch[0], ch[1], ch[2], b0, b1, b2);
    MFMA6(acc, cl[0], cl[1], cl[2], b0, b1, b2);
    int ow = OW0 + 16 * wsub + la;
#pragma unroll
    for (int r = 0; r < 4; ++r) {
      int oh = OH0 + 16 * osb + 4 * lg + r;
      op[(size_t)oh * W_OUT + ow] = acc[r];
    }
  }
}

extern "C" void kernel_launch(void* const* d_in, const int* in_sizes, int n_in,
                              void* d_out, int out_size, void* d_ws, size_t ws_size,
                              hipStream_t stream) {
  const float* x = (const float*)d_in[0];   // (8,32,512,512) fp32
  float* out = (float*)d_out;               // (8,32,256,256) fp32

  const size_t GT_BYTES = (size_t)256 * GT_P * 2;  // 64 MiB bf16
  if (ws_size >= GT_BYTES) {
    unsigned short* gtg = (unsigned short*)d_ws;
    dim3 ga(32, 256);          // grow-stripe x plane
    afs_h<<<ga, 256, 0, stream>>>(x, gtg);
    dim3 gb(4, 4, 256);        // oh-stripe x w-quarter x plane
    afs_v<<<gb, 256, 0, stream>>>(gtg, out);
  } else {
    dim3 g(4, 4, 256);
    afs_fused<<<g, 512, 0, stream>>>(x, out);
  }
}